// Round 5
// baseline (302.105 us; speedup 1.0000x reference)
//
#include <hip/hip_runtime.h>
#include <hip/hip_bf16.h>

constexpr int kS   = 32;
constexpr int kB   = 256;
constexpr int kIN  = 1024;
constexpr int kOUT = 1024;
constexpr int BN   = 64;         // o-cols per block (GEMM)
constexpr int BK   = 32;         // k per tile (one MFMA K)
constexpr int NT   = kIN / BK;   // 32 tiles

typedef __bf16 v4bf __attribute__((ext_vector_type(4)));
typedef __bf16 v8bf __attribute__((ext_vector_type(8)));
typedef float  v4f  __attribute__((ext_vector_type(4)));

__device__ __forceinline__ float softplus_f(float x) {
    return fmaxf(x, 0.0f) + log1pf(expf(-fabsf(x)));
}
__device__ __forceinline__ unsigned int bfbits(float x) {
    __bf16 h = (__bf16)x;
    unsigned short u;
    __builtin_memcpy(&u, &h, 2);
    return (unsigned int)u;
}
__device__ __forceinline__ float asf(unsigned int u) {
    float f; __builtin_memcpy(&f, &u, 4); return f;
}

// pack (bf16(mu) low, bf16(softplus(rho)) high) into u32 per weight element
__global__ void sigma_pack(const float* __restrict__ mu, const float* __restrict__ rho,
                           uint4* __restrict__ ms) {
    int gid = blockIdx.x * blockDim.x + threadIdx.x;  // 4 elems/thread
    float4 m = reinterpret_cast<const float4*>(mu)[gid];
    float4 r = reinterpret_cast<const float4*>(rho)[gid];
    uint4 o;
    o.x = bfbits(m.x) | (bfbits(softplus_f(r.x)) << 16);
    o.y = bfbits(m.y) | (bfbits(softplus_f(r.y)) << 16);
    o.z = bfbits(m.z) | (bfbits(softplus_f(r.z)) << 16);
    o.w = bfbits(m.w) | (bfbits(softplus_f(r.w)) << 16);
    ms[gid] = o;
}

// cast X fp32 -> bf16 workspace, 8 elems/thread
__global__ void xcast_kernel(const float* __restrict__ X, __bf16* __restrict__ Xb) {
    size_t i = ((size_t)blockIdx.x * blockDim.x + threadIdx.x) * 8;
    float4 a = *reinterpret_cast<const float4*>(X + i);
    float4 b = *reinterpret_cast<const float4*>(X + i + 4);
    v8bf r;
    r[0] = (__bf16)a.x; r[1] = (__bf16)a.y; r[2] = (__bf16)a.z; r[3] = (__bf16)a.w;
    r[4] = (__bf16)b.x; r[5] = (__bf16)b.y; r[6] = (__bf16)b.z; r[7] = (__bf16)b.w;
    *reinterpret_cast<v8bf*>(Xb + i) = r;
}

// Pass C: materialize W' = mu + sigma*eps (bf16) in GEMM-tiled swizzled layout.
// W'[s][ot][t][64 rows][32 k], tile = 4 KB; within tile, the 16B k-slot is
// XOR-swizzled: slot = (k>>3 & 3) ^ ((row>>1) & 3)  (conflict-free b128 reads
// in pass D). LDS-free, barrier-free: eps read in full-wave 1 KB contiguous
// bursts (4 KB sequential per row -> DRAM-page friendly); 8-16B swizzled
// stores aggregate to full lines in L2/L3.
__global__ __launch_bounds__(256, 4) void wmat(
        const unsigned int* __restrict__ MS,    // [OUT][IN] packed (mu,sigma)
        const float* __restrict__ Ew,           // [S][OUT][IN]
        __bf16* __restrict__ Wp)                // tiled output, 64 MB
{
    const int bb  = blockIdx.x;               // 2048 blocks
    const int s   = bb & 31;
    const int rr  = bb >> 5;                  // 0..63
    const int ot  = rr >> 2;                  // 0..15
    const int q   = rr & 3;                   // row-quarter of the 64-row slice
    const int tid = threadIdx.x;

    const float*        Eg = Ew + ((size_t)s * kOUT + ot * 64) * kIN;
    const unsigned int* Mg = MS + (size_t)(ot * 64) * kIN;
    char* Wt = (char*)(Wp + ((size_t)(s * 16 + ot) * NT) * 2048);  // 32 tiles x 4KB

    #pragma unroll 4
    for (int i = tid; i < 16 * 256; i += 256) {
        int row = q * 16 + (i >> 8);          // 0..63 within slice
        int k   = (i & 255) * 4;              // 0..1020
        float4 e = *reinterpret_cast<const float4*>(Eg + (size_t)row * kIN + k);
        uint4  p = *reinterpret_cast<const uint4*>(Mg + (size_t)row * kIN + k);
        v4bf w;
        w[0] = (__bf16)fmaf(asf(p.x & 0xffff0000u), e.x, asf(p.x << 16));
        w[1] = (__bf16)fmaf(asf(p.y & 0xffff0000u), e.y, asf(p.y << 16));
        w[2] = (__bf16)fmaf(asf(p.z & 0xffff0000u), e.z, asf(p.z << 16));
        w[3] = (__bf16)fmaf(asf(p.w & 0xffff0000u), e.w, asf(p.w << 16));
        int t    = k >> 5;
        int slot = ((k >> 3) & 3) ^ ((row >> 1) & 3);
        *reinterpret_cast<v4bf*>(Wt + t * 4096 + row * 64 + slot * 16 + (k & 7) * 2) = w;
    }
}

// async global->LDS (no result VGPRs; lds dest = uniform base + lane*size)
#define GLDS16(g, l) __builtin_amdgcn_global_load_lds(                      \
    (const __attribute__((address_space(1))) void*)(g),                     \
    (__attribute__((address_space(3))) void*)(l), 16, 0, 0)
#define GLDS4(g, l) __builtin_amdgcn_global_load_lds(                       \
    (const __attribute__((address_space(1))) void*)(g),                     \
    (__attribute__((address_space(3))) void*)(l), 4, 0, 0)

// Pass D: pure bf16 GEMM on pre-materialized W' tiles. v4's counted-vmcnt
// GLDS ring (verified): per wave per tile 2x GLDS16 (X) + 2x GLDS4 (W') = 4
// vm-ops; vmcnt(4) mid-loop keeps tile t+1 in flight, lgkmcnt(0)+raw barrier
// closes the 3-ring reuse hazard. W' tile = 4 KB CONTIGUOUS (the DRAM-
// efficiency fix), L3-warm from pass C. LDS 60 KB -> 2 blocks/CU (16 waves).
__global__ __launch_bounds__(512, 4) void dv_gemm(
        const __bf16* __restrict__ Xb,          // [S][B][IN] bf16
        const __bf16* __restrict__ Wp,          // tiled W'
        const float* __restrict__ Bmu,          // [OUT]
        const float* __restrict__ Brho,         // [OUT]
        const float* __restrict__ Eb,           // [S][OUT]
        float* __restrict__ O)                  // [S][B][OUT]
{
    __shared__ __attribute__((aligned(16))) __bf16 Xs[3][kB * BK];  // 3 x 16 KB
    __shared__ __attribute__((aligned(16))) __bf16 Ws[3][BN * BK];  // 3 x  4 KB

    const int tid = threadIdx.x, bb = blockIdx.x;
    const int xcd = bb & 7;
    const int jj  = bb >> 3;                   // 0..63
    const int s   = (xcd << 2) | (jj & 3);     // 4 s-values per XCD -> X L2-resident
    const int ot  = jj >> 2;                   // 0..15
    const int o_base = ot * BN;

    const int lane = tid & 63, wv = tid >> 6;  // wv 0..7
    const int mwv = wv >> 1, nwv = wv & 1;     // 4M x 2N wave grid
    const int lr = lane & 15, kg = lane >> 4;

    const __bf16* Xbase = Xb + (size_t)s * kB * kIN;
    const char*   Wbase = (const char*)(Wp + ((size_t)(s * 16 + ot) * NT) * 2048);

    // X staging source rows (r0-verified quarter-rotation)
    const int xrow = wv * 32 + (lane >> 2);
    const int xq0  = ((lane & 3) - (xrow >> 2)) & 3;
    const int xq1  = ((lane & 3) - ((xrow + 16) >> 2)) & 3;

    auto STAGE = [&](int t, int bf) {
        GLDS16(Xbase + (size_t)xrow * kIN + t * BK + xq0 * 8,
               &Xs[bf][(wv * 32) * BK]);
        GLDS16(Xbase + (size_t)(xrow + 16) * kIN + t * BK + xq1 * 8,
               &Xs[bf][(wv * 32 + 16) * BK]);
        const char* wt = Wbase + t * 4096 + wv * 512;
        char*       wl = (char*)&Ws[bf][0] + wv * 512;
        GLDS4(wt + lane * 4,       wl);
        GLDS4(wt + 256 + lane * 4, wl + 256);
    };

    v4f acc[4][2] = {};

    STAGE(0, 0);
    STAGE(1, 1);

    for (int t = 0; t < NT; ++t) {
        const int bf = t % 3;

        if (t < NT - 1)
            asm volatile("s_waitcnt vmcnt(4) lgkmcnt(0)" ::: "memory");
        else
            asm volatile("s_waitcnt vmcnt(0) lgkmcnt(0)" ::: "memory");
        __builtin_amdgcn_s_barrier();          // raw: no compiler vmcnt(0) drain

        if (t + 2 < NT) STAGE(t + 2, (t + 2) % 3);

        // ---- A frags (r0-verified layout) ----
        v8bf a[4];
        #pragma unroll
        for (int mf = 0; mf < 4; ++mf) {
            int row = mwv * 64 + mf * 16 + lr;
            int ql  = (kg + (row >> 2)) & 3;
            a[mf] = *reinterpret_cast<const v8bf*>(&Xs[bf][row * BK + ql * 8]);
        }
        // ---- B frags: one b128 per nf, swizzle matches wmat ----
        v8bf b[2];
        #pragma unroll
        for (int nf = 0; nf < 2; ++nf) {
            int row  = nwv * 32 + nf * 16 + lr;
            int slot = kg ^ ((row >> 1) & 3);
            b[nf] = *reinterpret_cast<const v8bf*>(
                (const char*)&Ws[bf][0] + row * 64 + slot * 16);
        }

        #pragma unroll
        for (int mf = 0; mf < 4; ++mf)
            #pragma unroll
            for (int nf = 0; nf < 2; ++nf)
                acc[mf][nf] = __builtin_amdgcn_mfma_f32_16x16x32_bf16(
                    a[mf], b[nf], acc[mf][nf], 0, 0, 0);
    }

    // ---- epilogue: inline-sampled bias + nontemporal store ----
    float bias[2];
    #pragma unroll
    for (int nf = 0; nf < 2; ++nf) {
        int o = o_base + nwv * 32 + nf * 16 + lr;
        bias[nf] = fmaf(softplus_f(Brho[o]), Eb[(size_t)s * kOUT + o], Bmu[o]);
    }
    #pragma unroll
    for (int mf = 0; mf < 4; ++mf) {
        #pragma unroll
        for (int rr = 0; rr < 4; ++rr) {
            int mrow = mwv * 64 + mf * 16 + kg * 4 + rr;  // C/D: row=(lane>>4)*4+reg
            float* orow = O + ((size_t)s * kB + mrow) * kOUT + o_base + nwv * 32;
            #pragma unroll
            for (int nf = 0; nf < 2; ++nf)
                __builtin_nontemporal_store(acc[mf][nf][rr] + bias[nf],
                                            orow + nf * 16 + lr);  // col = lane&15
        }
    }
}

// safety-net fallback (never expected: workspace is >=512 MB per harness fill)
__global__ void dv_naive(const float* __restrict__ X, const float* __restrict__ Wmu,
                         const float* __restrict__ Wrho, const float* __restrict__ Bmu,
                         const float* __restrict__ Brho, const float* __restrict__ Ew,
                         const float* __restrict__ Eb, float* __restrict__ O) {
    size_t gid = (size_t)blockIdx.x * blockDim.x + threadIdx.x;  // s*B*OUT
    int o = gid % kOUT;
    int b = (gid / kOUT) % kB;
    int s = gid / ((size_t)kOUT * kB);
    const float* x = X + ((size_t)s * kB + b) * kIN;
    const float* e = Ew + ((size_t)s * kOUT + o) * kIN;
    const float* wm = Wmu + (size_t)o * kIN;
    const float* wr = Wrho + (size_t)o * kIN;
    float acc = 0.f;
    for (int k = 0; k < kIN; ++k)
        acc += x[k] * fmaf(softplus_f(wr[k]), e[k], wm[k]);
    O[gid] = acc + fmaf(softplus_f(Brho[o]), Eb[(size_t)s * kOUT + o], Bmu[o]);
}

extern "C" void kernel_launch(void* const* d_in, const int* in_sizes, int n_in,
                              void* d_out, int out_size, void* d_ws, size_t ws_size,
                              hipStream_t stream) {
    const float* input = (const float*)d_in[0];
    const float* w_mu  = (const float*)d_in[1];
    const float* w_rho = (const float*)d_in[2];
    const float* b_mu  = (const float*)d_in[3];
    const float* b_rho = (const float*)d_in[4];
    const float* eps_w = (const float*)d_in[5];
    const float* eps_b = (const float*)d_in[6];
    float* out = (float*)d_out;

    const size_t ms_bytes  = (size_t)kOUT * kIN * 4;                  //  4 MB
    const size_t xbf_bytes = (size_t)kS * kB * kIN * sizeof(__bf16);  // 16 MB
    const size_t wp_bytes  = (size_t)kS * kOUT * kIN * sizeof(__bf16);// 64 MB

    if (ws_size < ms_bytes + xbf_bytes + wp_bytes) {
        dv_naive<<<dim3((size_t)kS * kB * kOUT / 256), 256, 0, stream>>>(
            input, w_mu, w_rho, b_mu, b_rho, eps_w, eps_b, out);
        return;
    }

    unsigned int* ms = (unsigned int*)d_ws;
    __bf16* xbf = (__bf16*)((char*)d_ws + ms_bytes);
    __bf16* wp  = (__bf16*)((char*)d_ws + ms_bytes + xbf_bytes);

    sigma_pack<<<dim3((kOUT * kIN) / (256 * 4)), 256, 0, stream>>>(w_mu, w_rho, (uint4*)ms);
    xcast_kernel<<<dim3((size_t)kS * kB * kIN / (256 * 8)), 256, 0, stream>>>(input, xbf);
    wmat<<<dim3(2048), 256, 0, stream>>>(ms, eps_w, wp);
    dv_gemm<<<dim3(kS * (kOUT / BN)), 512, 0, stream>>>(xbf, wp, b_mu, b_rho, eps_b, out);
}